// Round 10
// baseline (462.411 us; speedup 1.0000x reference)
//
#include <hip/hip_runtime.h>
#include <hip/hip_bf16.h>
#include <cstdint>
#include <cstddef>

#define NB 32
#define NS 4096
#define NH 512
#define NK 1024   // 2H

typedef __attribute__((ext_vector_type(8))) short short8;
typedef __attribute__((ext_vector_type(4))) float f32x4;

#define SB() __builtin_amdgcn_sched_barrier(0)
#define LGKM0() asm volatile("s_waitcnt lgkmcnt(0)" ::: "memory")
#define VMC(n) asm volatile("s_waitcnt vmcnt(" #n ")" ::: "memory")
#define BAR() __builtin_amdgcn_s_barrier()

__device__ __forceinline__ unsigned short f2bf_s(float f) {
  union { float f; unsigned u; } x; x.f = f;
  unsigned r = x.u + 0x7fffu + ((x.u >> 16) & 1u);   // RNE bf16
  return (unsigned short)(r >> 16);
}

__device__ __forceinline__ unsigned pk2(float lo, float hi) {
  __hip_bfloat162 h = __float22bfloat162_rn(float2{lo, hi});
  union { __hip_bfloat162 h; unsigned u; } c; c.h = h;
  return c.u;
}

__device__ __forceinline__ void gload16(const void* g, void* l) {
  __builtin_amdgcn_global_load_lds(
      (const __attribute__((address_space(1))) unsigned int*)g,
      (__attribute__((address_space(3))) unsigned int*)l, 16, 0, 0);
}

// ---- kernel 1: pack Ua [512 n][1024 k] f32 -> bf16, LINEAR BK=32 slices ----
// out 16B-chunk t: s=t&3, n=(t>>2)&255, kc=(t>>10)&31, bn=t>>15
// content: bf16 ua[bn*256+n][kc*32 + s*8 + j], j=0..7
__global__ void k_ua_pack(const float* __restrict__ ua, unsigned short* __restrict__ out) {
  int t = blockIdx.x * 256 + threadIdx.x;   // 65536 chunks of 16B
  int s  = t & 3;
  int n  = (t >> 2) & 255;
  int kc = (t >> 10) & 31;
  int bn = t >> 15;
  const float* src = ua + (size_t)(bn * 256 + n) * NK + kc * 32 + s * 8;
  float4 a  = *(const float4*)src;
  float4 b2 = *(const float4*)(src + 4);
  uint4 o;
  o.x = pk2(a.x, a.y);   o.y = pk2(a.z, a.w);
  o.z = pk2(b2.x, b2.y); o.w = pk2(b2.z, b2.w);
  *(uint4*)(out + (size_t)t * 8) = o;
}

// ---- kernel 2: qproj[b][h] = query[b]·Wa_w[h] + Wa_b[h] + Ua_b[h] ----
__global__ void k_qproj(const float* __restrict__ q, const float* __restrict__ ww,
                        const float* __restrict__ wb, const float* __restrict__ ub,
                        float* __restrict__ qp) {
  int b = blockIdx.y;
  int h = blockIdx.x * 128 + threadIdx.x;
  const float* qr = q + b * NH;
  const float* wr = ww + h * NH;
  float acc = 0.f;
  for (int k = 0; k < NH; k += 4) {
    float4 a = *(const float4*)(qr + k);
    float4 c = *(const float4*)(wr + k);
    acc += a.x * c.x + a.y * c.y + a.z * c.z + a.w * c.w;
  }
  qp[b * NH + h] = acc + wb[h] + ub[h];
}

// ---- kernel 3: scores partials. A = f32 keys via gload_lds (XOR-preswizzled source),
// cvt_pk on LDS-read. B = bf16 linear pack via gload_lds. BK=32, 32 K-chunks.
// COUNTED vmcnt pipeline: tiles t,t+1 resident (dbuf); t+2 issued after t's last read;
// per-kc gate vmcnt(6) — never drains to 0 until the K-tail.
// grid (16 sblk, 2 bn, 32 b), 512 thr = 8 waves = 2 rg x 4 cg, wave tile 128x64.
__global__ __launch_bounds__(512, 1)
void k_scores9(const float* __restrict__ keys, const unsigned short* __restrict__ uapk,
               const float* __restrict__ qproj, const float* __restrict__ vaw,
               float* __restrict__ scores_part) {
  __shared__ alignas(16) float          Albuf[2][256 * 32];     // 2 x 32KB (f32, XOR-swizzled rows)
  __shared__ alignas(16) unsigned short Blbuf[2][256 * 32];     // 2 x 16KB (bf16, linear 64B rows)
  __shared__ float qp_s[256];
  __shared__ float va_s[256];
  __shared__ float red[256][4];

  const int sblk = blockIdx.x;
  const int bn   = blockIdx.y;
  const int b    = blockIdx.z;
  const int tid  = threadIdx.x;
  const int w    = tid >> 6;
  const int l    = tid & 63;
  const int rg   = w >> 2;      // 0..1
  const int cg   = w & 3;       // 0..3
  const int l15  = l & 15;
  const int lq   = l >> 4;      // 0..3

  if (tid < 256) {
    qp_s[tid] = qproj[b * NH + bn * 256 + tid];
    va_s[tid] = vaw[bn * 256 + tid];
  }
  __syncthreads();   // drain before any prefetch is in flight

  // ---- A staging addresses: LDS[row][s16] holds global k-chunk gs = s16 ^ (row&7).
  // gload j writes LDS bytes [w*4096 + j*1024 + l*16]; lane -> row = w*32+j*8+(l>>3),
  // s16 = l&7  ->  global chunk gs = (l&7) ^ (l>>3).
  const int l3 = l >> 3;
  const int gsx = (l & 7) ^ l3;
  const float* aglane = keys + ((size_t)b * NS + sblk * 256 + w * 32 + l3) * NK + gsx * 4;
  // ---- B staging: linear; per wave 2KB per kc
  const char* bglane = (const char*)uapk + (size_t)bn * 524288 + w * 2048 + l * 16;

  f32x4 acc[8][4];
  #pragma unroll
  for (int i = 0; i < 8; ++i)
    #pragma unroll
    for (int j = 0; j < 4; ++j)
      acc[i][j] = (f32x4){0.f, 0.f, 0.f, 0.f};

  // stage tile kc: A = 4 gloads/wave, B = 2 gloads/wave (6 total)
  #define STAGE(kc_, buf_)                                                          \
    {                                                                               \
      _Pragma("unroll")                                                             \
      for (int j = 0; j < 4; ++j)                                                   \
        gload16(aglane + (size_t)j * 8 * NK + (kc_) * 32,                           \
                (char*)&Albuf[buf_][0] + w * 4096 + j * 1024);                      \
      _Pragma("unroll")                                                             \
      for (int j = 0; j < 2; ++j)                                                   \
        gload16(bglane + (size_t)(kc_) * 16384 + j * 1024,                          \
                (char*)&Blbuf[buf_][0] + w * 2048 + j * 1024);                      \
    }

  // prologue: tiles 0 and 1
  STAGE(0, 0)
  STAGE(1, 1)
  VMC(6);   // tile0 landed; tile1's 6 in flight
  SB(); BAR();

  for (int kc = 0; kc < 32; ++kc) {
    const int cur = kc & 1;
    const char* Ab = (const char*)&Albuf[cur][0];
    const char* Bb = (const char*)&Blbuf[cur][0];
    short8 bf[4], af[4];

    // ===== ph0: read B frags + A rowtiles 0-3 (f32 -> cvt_pk) =====
    #pragma unroll
    for (int ct = 0; ct < 4; ++ct)
      bf[ct] = *(const short8*)(Bb + (cg * 64 + ct * 16 + l15) * 64 + lq * 16);
    #pragma unroll
    for (int rt = 0; rt < 4; ++rt) {
      int row = rg * 128 + rt * 16 + l15;
      int off0 = row * 128 + (((lq * 2) ^ (row & 7)) << 4);
      float4 f0 = *(const float4*)(Ab + off0);
      float4 f1 = *(const float4*)(Ab + (off0 ^ 16));
      uint4 q;
      q.x = pk2(f0.x, f0.y); q.y = pk2(f0.z, f0.w);
      q.z = pk2(f1.x, f1.y); q.w = pk2(f1.z, f1.w);
      union { uint4 u; short8 s; } cv; cv.u = q;
      af[rt] = cv.s;
    }
    SB(); BAR(); LGKM0(); SB();
    __builtin_amdgcn_s_setprio(1);
    #pragma unroll
    for (int rt = 0; rt < 4; ++rt)
      #pragma unroll
      for (int ct = 0; ct < 4; ++ct)
        acc[rt][ct] = __builtin_amdgcn_mfma_f32_16x16x32_bf16(af[rt], bf[ct], acc[rt][ct], 0, 0, 0);
    __builtin_amdgcn_s_setprio(0);
    SB(); BAR();

    // ===== ph1: A rowtiles 4-7; MFMA with held bf =====
    #pragma unroll
    for (int rt = 0; rt < 4; ++rt) {
      int row = rg * 128 + (4 + rt) * 16 + l15;
      int off0 = row * 128 + (((lq * 2) ^ (row & 7)) << 4);
      float4 f0 = *(const float4*)(Ab + off0);
      float4 f1 = *(const float4*)(Ab + (off0 ^ 16));
      uint4 q;
      q.x = pk2(f0.x, f0.y); q.y = pk2(f0.z, f0.w);
      q.z = pk2(f1.x, f1.y); q.w = pk2(f1.z, f1.w);
      union { uint4 u; short8 s; } cv; cv.u = q;
      af[rt] = cv.s;
    }
    SB(); BAR(); LGKM0(); SB();
    __builtin_amdgcn_s_setprio(1);
    #pragma unroll
    for (int rt = 0; rt < 4; ++rt)
      #pragma unroll
      for (int ct = 0; ct < 4; ++ct)
        acc[4 + rt][ct] = __builtin_amdgcn_mfma_f32_16x16x32_bf16(af[rt], bf[ct], acc[4 + rt][ct], 0, 0, 0);
    __builtin_amdgcn_s_setprio(0);
    SB(); BAR();
    // all waves past MFMA => all reads of buf[cur] complete => safe to overwrite

    // ===== tile boundary: issue t+2 into buf[cur]; counted gate for t+1 =====
    if (kc <= 29) {
      STAGE(kc + 2, cur)
      VMC(6);          // wait tile kc+1 (oldest 6); allow tile kc+2's 6 in flight
      SB(); BAR();
    } else if (kc == 30) {
      VMC(0);          // tail: tile 31 (issued at kc=29) must land; nothing else in flight
      SB(); BAR();
    }
  }

  // ---- epilogue (R3-verified): partial score over this block's 256 n-cols ----
  #pragma unroll
  for (int rt = 0; rt < 8; ++rt) {
    #pragma unroll
    for (int reg = 0; reg < 4; ++reg) {
      float sum = 0.f;
      #pragma unroll
      for (int ct = 0; ct < 4; ++ct) {
        int gn = cg * 64 + ct * 16 + l15;
        float x = qp_s[gn] + acc[rt][ct][reg];
        float e = __expf(2.f * x);
        float th = 1.f - __fdividef(2.f, e + 1.f);
        sum += va_s[gn] * th;
      }
      sum += __shfl_xor(sum, 1);
      sum += __shfl_xor(sum, 2);
      sum += __shfl_xor(sum, 4);
      sum += __shfl_xor(sum, 8);
      if (l15 == 0)
        red[rg * 128 + rt * 16 + lq * 4 + reg][cg] = sum;
    }
  }
  __syncthreads();
  if (tid < 256) {
    float s = red[tid][0] + red[tid][1] + red[tid][2] + red[tid][3];
    scores_part[((size_t)bn * NB + b) * NS + sblk * 256 + tid] = s;
  }
  #undef STAGE
}

// ---- kernel 4: softmax over (part0 + part1 + vab) -> attn out ----
__global__ void k_softmax(const float* __restrict__ sp, const float* __restrict__ vab,
                          float* __restrict__ attn) {
  __shared__ float redm[4];
  __shared__ float reds[4];
  int b = blockIdx.x, tid = threadIdx.x;
  const float* r0 = sp + (size_t)b * NS;
  const float* r1 = sp + (size_t)(NB + b) * NS;
  float vb = vab[0];
  float v[16];
  float m = -1e30f;
  #pragma unroll
  for (int i = 0; i < 16; ++i) {
    int idx = i * 256 + tid;
    v[i] = r0[idx] + r1[idx] + vb;
    m = fmaxf(m, v[i]);
  }
  #pragma unroll
  for (int off = 1; off < 64; off <<= 1) m = fmaxf(m, __shfl_xor(m, off));
  if ((tid & 63) == 0) redm[tid >> 6] = m;
  __syncthreads();
  m = fmaxf(fmaxf(redm[0], redm[1]), fmaxf(redm[2], redm[3]));
  float s = 0.f;
  #pragma unroll
  for (int i = 0; i < 16; ++i) { v[i] = expf(v[i] - m); s += v[i]; }
  #pragma unroll
  for (int off = 1; off < 64; off <<= 1) s += __shfl_xor(s, off);
  if ((tid & 63) == 0) reds[tid >> 6] = s;
  __syncthreads();
  s = reds[0] + reds[1] + reds[2] + reds[3];
  float inv = 1.f / s;
  float* o = attn + (size_t)b * NS;
  #pragma unroll
  for (int i = 0; i < 16; ++i) o[i * 256 + tid] = v[i] * inv;
}

// ---- kernel 5: context partials (8 segments of 512 s-rows) ----
__global__ void k_ctx_partial(const float* __restrict__ keys, const float* __restrict__ attn,
                              float* __restrict__ part) {
  __shared__ float w_s[512];
  int b = blockIdx.y, seg = blockIdx.x, tid = threadIdx.x;
  int sbeg = seg * 512;
  w_s[tid] = attn[(size_t)b * NS + sbeg + tid];
  w_s[tid + 256] = attn[(size_t)b * NS + sbeg + 256 + tid];
  __syncthreads();
  const float* kp = keys + ((size_t)b * NS + sbeg) * NK + tid * 4;
  float ax = 0.f, ay = 0.f, az = 0.f, aw = 0.f;
  #pragma unroll 4
  for (int s = 0; s < 512; ++s) {
    float4 kv = *(const float4*)(kp + (size_t)s * NK);
    float wv = w_s[s];
    ax += wv * kv.x; ay += wv * kv.y; az += wv * kv.z; aw += wv * kv.w;
  }
  float4 o; o.x = ax; o.y = ay; o.z = az; o.w = aw;
  *(float4*)(part + ((size_t)(seg * NB + b) << 10) + tid * 4) = o;
}

// ---- kernel 6: reduce 8 segment partials -> context ----
__global__ void k_ctx_reduce(const float* __restrict__ part, float* __restrict__ ctx) {
  int i = blockIdx.x * 256 + threadIdx.x;   // 32768
  int b = i >> 10, c = i & 1023;
  float s = 0.f;
  #pragma unroll
  for (int seg = 0; seg < 8; ++seg) s += part[((size_t)(seg * NB + b) << 10) + c];
  ctx[i] = s;
}

extern "C" void kernel_launch(void* const* d_in, const int* in_sizes, int n_in,
                              void* d_out, int out_size, void* d_ws, size_t ws_size,
                              hipStream_t stream) {
  const float* query = (const float*)d_in[0];
  const float* keys  = (const float*)d_in[1];
  const float* Wa_w  = (const float*)d_in[2];
  const float* Wa_b  = (const float*)d_in[3];
  const float* Ua_w  = (const float*)d_in[4];
  const float* Ua_b  = (const float*)d_in[5];
  const float* Va_w  = (const float*)d_in[6];
  const float* Va_b  = (const float*)d_in[7];

  float* out      = (float*)d_out;
  float* ctx_out  = out;             // [32][1024]
  float* attn_out = out + NB * NK;   // [32][4096]

  unsigned short* ua_pk = (unsigned short*)d_ws;                       // 1 MB
  float* qproj  = (float*)((char*)d_ws + (1u << 20));                  // 64 KB
  float* spart  = (float*)((char*)d_ws + (1u << 20) + (1u << 16));     // 1 MB (2 partials)
  float* part   = (float*)((char*)d_ws + (2u << 20) + (1u << 16));     // 1 MB

  k_ua_pack<<<256, 256, 0, stream>>>(Ua_w, ua_pk);
  k_qproj<<<dim3(4, NB), 128, 0, stream>>>(query, Wa_w, Wa_b, Ua_b, qproj);
  k_scores9<<<dim3(16, 2, NB), 512, 0, stream>>>(keys, ua_pk, qproj, Va_w, spart);
  k_softmax<<<NB, 256, 0, stream>>>(spart, Va_b, attn_out);
  k_ctx_partial<<<dim3(8, NB), 256, 0, stream>>>(keys, attn_out, part);
  k_ctx_reduce<<<NB * NK / 256, 256, 0, stream>>>(part, ctx_out);
}